// Round 1
// baseline (4124.266 us; speedup 1.0000x reference)
//
#include <hip/hip_runtime.h>
#include <math.h>

#define TT 200
#define PD 33   // padded leading dim for row-scalar-read matrices

__device__ __forceinline__ float rdlane(float v, int l) {
  return __int_as_float(__builtin_amdgcn_readlane(__float_as_int(v), l));
}

#if __has_builtin(__builtin_amdgcn_rsqf)
#define RSQF(x) __builtin_amdgcn_rsqf(x)
#else
#define RSQF(x) (1.0f / sqrtf(x))
#endif

__device__ __forceinline__ float4 ld4(const float* p) { return *(const float4*)p; }
__device__ __forceinline__ void st4(float* p, float4 v) { *(float4*)p = v; }
__device__ __forceinline__ void fma4(float4& acc, float a, float4 b) {
  acc.x = fmaf(a, b.x, acc.x);
  acc.y = fmaf(a, b.y, acc.y);
  acc.z = fmaf(a, b.z, acc.z);
  acc.w = fmaf(a, b.w, acc.w);
}

__global__ void __launch_bounds__(256) kf_kernel(
    const float* __restrict__ Yg, const float* __restrict__ Ug,
    const float* __restrict__ Mg, const float* __restrict__ Ag,
    const float* __restrict__ Bg, const float* __restrict__ Cg,
    const float* __restrict__ mu0g, const float* __restrict__ S0g,
    const float* __restrict__ Qg, const float* __restrict__ Rg,
    float* __restrict__ out, int Bsz)
{
  // padded (stride-33) left-operand buffers
  __shared__ __align__(16) float Apad[32*PD], Cpad[32*PD], PAD1[32*PD], PAD2[32*PD];
  // stride-32 buffers (f4 right-operand / column reads)
  __shared__ __align__(16) float AT32[32*32], C32[32*32], CT32[32*32];
  __shared__ __align__(16) float Sigma32[32*32], SigP32[32*32], KT32[32*32], JT32[32*32];
  __shared__ __align__(16) float BUFA[32*32], BUFB[32*32], BUFC[32*32];
  __shared__ float u_lds[16], y_lds[32], mupred[32], r_lds[32], mu_lds[32], mlds[1];

  const int tid = threadIdx.x;
  const int mi = tid >> 3;          // output row 0..31
  const int mj = (tid & 7) << 2;    // output col group (4 wide)
  const int b = blockIdx.x;
  const long btB = (long)b * TT;

  const long o_Sf = (long)Bsz * TT * 32;
  const long o_mp = o_Sf + (long)Bsz * TT * 32 * 32;
  const long o_Sp = o_mp + (long)Bsz * TT * 32;

  // constants + initial state
  for (int e = tid; e < 1024; e += 256) {
    int i = e >> 5, k = e & 31;
    float a = Ag[e];
    Apad[i*PD + k] = a; AT32[k*32 + i] = a;
    float c = Cg[e];
    Cpad[i*PD + k] = c; C32[e] = c; CT32[k*32 + i] = c;
    Sigma32[e] = S0g[e];
  }
  if (tid < 32) mu_lds[tid] = mu0g[tid];
  __syncthreads();

  for (int t = 0; t < TT; ++t) {
    const long bt = btB + t;

    // ---- P1: T1(PAD1) = A @ Sigma ; stage u, y, mask ----
    {
      float4 acc = {0.f, 0.f, 0.f, 0.f};
      const int ro = mi * PD;
      #pragma unroll
      for (int k = 0; k < 32; ++k) {
        float a = Apad[ro + k];
        fma4(acc, a, ld4(Sigma32 + k*32 + mj));
      }
      PAD1[ro+mj] = acc.x; PAD1[ro+mj+1] = acc.y; PAD1[ro+mj+2] = acc.z; PAD1[ro+mj+3] = acc.w;
      if (tid < 16) u_lds[tid] = Ug[bt*16 + tid];
      if (tid >= 64 && tid < 96) y_lds[tid-64] = Yg[bt*32 + (tid-64)];
      if (tid == 224) mlds[0] = Mg[bt];
    }
    __syncthreads();

    // ---- P2: SigP = T1 @ A^T + Q ; mu_pred = A mu + Bm u ----
    {
      float4 acc = {0.f, 0.f, 0.f, 0.f};
      const int ro = mi * PD;
      #pragma unroll
      for (int k = 0; k < 32; ++k) {
        float a = PAD1[ro + k];
        fma4(acc, a, ld4(AT32 + k*32 + mj));
      }
      float4 q4 = ld4(Qg + mi*32 + mj);
      acc.x += q4.x; acc.y += q4.y; acc.z += q4.z; acc.w += q4.w;
      st4(SigP32 + mi*32 + mj, acc);
      if (tid < 32) {
        float s = 0.f;
        #pragma unroll
        for (int k = 0; k < 32; ++k) s = fmaf(Apad[tid*PD + k], mu_lds[k], s);
        #pragma unroll
        for (int k = 0; k < 16; ++k) s = fmaf(Bg[tid*16 + k], u_lds[k], s);
        mupred[tid] = s;
      }
    }
    __syncthreads();

    // ---- P3: T2 = C @ SigP -> PAD2 (rows) + BUFA (stride32, solve RHS) ; r ----
    {
      float4 acc = {0.f, 0.f, 0.f, 0.f};
      const int ro = mi * PD;
      #pragma unroll
      for (int k = 0; k < 32; ++k) {
        float a = Cpad[ro + k];
        fma4(acc, a, ld4(SigP32 + k*32 + mj));
      }
      PAD2[ro+mj] = acc.x; PAD2[ro+mj+1] = acc.y; PAD2[ro+mj+2] = acc.z; PAD2[ro+mj+3] = acc.w;
      st4(BUFA + mi*32 + mj, acc);
      if (tid < 32) {
        float s = y_lds[tid];
        #pragma unroll
        for (int k = 0; k < 32; ++k) s = fmaf(-Cpad[tid*PD + k], mupred[k], s);
        r_lds[tid] = s;
      }
    }
    __syncthreads();

    // ---- P4: SS(BUFB) = T2 @ C^T + R ----
    {
      float4 acc = {0.f, 0.f, 0.f, 0.f};
      const int ro = mi * PD;
      #pragma unroll
      for (int k = 0; k < 32; ++k) {
        float a = PAD2[ro + k];
        fma4(acc, a, ld4(CT32 + k*32 + mj));
      }
      float4 r4 = ld4(Rg + mi*32 + mj);
      acc.x += r4.x; acc.y += r4.y; acc.z += r4.z; acc.w += r4.w;
      st4(BUFB + mi*32 + mj, acc);
    }
    __syncthreads();

    // ---- P5: S(BUFC) = 0.5*(SS + SS^T) ----
    {
      float4 v = ld4(BUFB + mi*32 + mj);
      float t0 = BUFB[(mj+0)*32 + mi];
      float t1 = BUFB[(mj+1)*32 + mi];
      float t2 = BUFB[(mj+2)*32 + mi];
      float t3 = BUFB[(mj+3)*32 + mi];
      float4 o = {0.5f*(v.x+t0), 0.5f*(v.y+t1), 0.5f*(v.z+t2), 0.5f*(v.w+t3)};
      st4(BUFC + mi*32 + mj, o);
    }
    __syncthreads();

    // ---- P6: wave0 = register Cholesky solve (S K^T = T2); waves1-3 = output writes ----
    if (tid < 64) {
      const int c = tid & 31;       // this lane owns column c (lanes 32-63 duplicate)
      float w[32], Lr[32], rr[32];
      float sd = 0.f;
      #pragma unroll
      for (int i = 0; i < 32; ++i) w[i] = BUFC[i*32 + c];   // column load: conflict-free
      const float mval = mlds[0];
      // Cholesky: lane c keeps full symmetric column; stale lanes self-zero.
      #pragma unroll
      for (int j = 0; j < 32; ++j) {
        float d = rdlane(w[j], j);       // final W[j][j]
        float s = RSQF(d);
        sd = (c == j) ? s : sd;          // lane j stores 1/L[j][j]
        float cj = w[j] * s;             // L[c][j]
        Lr[j] = cj;                      // lane c accumulates row c of L
        float scj = s * cj;
        #pragma unroll
        for (int i = j+1; i < 32; ++i)
          w[i] = fmaf(-rdlane(w[i], j), scj, w[i]);   // W[i][c] -= L[i][j]*L[c][j]
      }
      #pragma unroll
      for (int i = 0; i < 32; ++i) rr[i] = BUFA[i*32 + c];  // RHS column c (= T2[:,c])
      // forward: L z = rhs
      #pragma unroll
      for (int j = 0; j < 32; ++j) {
        float invd = rdlane(sd, j);
        float zj = rr[j] * invd;
        rr[j] = zj;
        #pragma unroll
        for (int i = j+1; i < 32; ++i)
          rr[i] = fmaf(-rdlane(Lr[j], i), zj, rr[i]); // L[i][j] from lane i
      }
      // backward: L^T x = z
      #pragma unroll
      for (int j = 31; j >= 0; --j) {
        float invd = rdlane(sd, j);
        float xj = rr[j] * invd;
        rr[j] = xj;
        #pragma unroll
        for (int i = 0; i < j; ++i)
          rr[i] = fmaf(-rdlane(Lr[i], j), xj, rr[i]); // L[j][i] from lane j
      }
      if (tid < 32) {
        #pragma unroll
        for (int p = 0; p < 32; ++p) KT32[p*32 + c] = mval * rr[p];  // masked K^T
      }
    } else {
      const int g0 = tid - 64;
      for (int g = g0; g < 256; g += 192)
        st4((float*)(out + o_Sp + bt*1024 + g*4), ld4(SigP32 + g*4));
      if (t > 0) {
        for (int g = g0; g < 256; g += 192)
          st4((float*)(out + o_Sf + (bt-1)*1024 + g*4), ld4(Sigma32 + g*4));
      }
      if (tid >= 192 && tid < 224) out[o_mp + bt*32 + (tid-192)] = mupred[tid-192];
      if (t > 0 && tid >= 224) out[(bt-1)*32 + (tid-224)] = mu_lds[tid-224];
    }
    __syncthreads();

    // ---- P7: J(PAD1) = I - K C ; RK(BUFC) = R @ K^T ; mu_new ----
    {
      float4 acc = {0.f, 0.f, 0.f, 0.f};
      float4 acc2 = {0.f, 0.f, 0.f, 0.f};
      #pragma unroll
      for (int k = 0; k < 32; ++k) {
        float a = KT32[k*32 + mi];              // K[mi][k]
        fma4(acc, a, ld4(C32 + k*32 + mj));
        float a2 = Rg[mi*32 + k];
        fma4(acc2, a2, ld4(KT32 + k*32 + mj));
      }
      const int ro = mi * PD;
      PAD1[ro+mj+0] = ((mi == mj+0) ? 1.f : 0.f) - acc.x;
      PAD1[ro+mj+1] = ((mi == mj+1) ? 1.f : 0.f) - acc.y;
      PAD1[ro+mj+2] = ((mi == mj+2) ? 1.f : 0.f) - acc.z;
      PAD1[ro+mj+3] = ((mi == mj+3) ? 1.f : 0.f) - acc.w;
      st4(BUFC + mi*32 + mj, acc2);
      if (tid < 32) {
        float s = mupred[tid];
        #pragma unroll
        for (int p = 0; p < 32; ++p) s = fmaf(KT32[p*32 + tid], r_lds[p], s);
        mu_lds[tid] = s;  // filtered mean
      }
    }
    __syncthreads();

    // ---- P8: X(PAD2) = J @ SigP ; JT32 = J^T ----
    {
      float4 acc = {0.f, 0.f, 0.f, 0.f};
      const int ro = mi * PD;
      #pragma unroll
      for (int k = 0; k < 32; ++k) {
        float a = PAD1[ro + k];
        fma4(acc, a, ld4(SigP32 + k*32 + mj));
      }
      PAD2[ro+mj] = acc.x; PAD2[ro+mj+1] = acc.y; PAD2[ro+mj+2] = acc.z; PAD2[ro+mj+3] = acc.w;
      float j0 = PAD1[(mj+0)*PD + mi];
      float j1 = PAD1[(mj+1)*PD + mi];
      float j2 = PAD1[(mj+2)*PD + mi];
      float j3 = PAD1[(mj+3)*PD + mi];
      float4 jt = {j0, j1, j2, j3};
      st4(JT32 + mi*32 + mj, jt);
    }
    __syncthreads();

    // ---- P9: SN(BUFB) = X @ J^T ; KK(BUFA) = K R K^T ----
    {
      float4 a1 = {0.f, 0.f, 0.f, 0.f};
      float4 a2 = {0.f, 0.f, 0.f, 0.f};
      const int ro = mi * PD;
      #pragma unroll
      for (int k = 0; k < 32; ++k) {
        float a = PAD2[ro + k];
        fma4(a1, a, ld4(JT32 + k*32 + mj));
        float x = KT32[k*32 + mi];
        fma4(a2, x, ld4(BUFC + k*32 + mj));
      }
      st4(BUFB + mi*32 + mj, a1);
      st4(BUFA + mi*32 + mj, a2);
    }
    __syncthreads();

    // ---- P10: Sigma = 0.5*(SN+SN^T) + 0.5*(KK+KK^T) ----
    {
      float4 v = ld4(BUFB + mi*32 + mj);
      float4 k4 = ld4(BUFA + mi*32 + mj);
      float s0 = BUFB[(mj+0)*32 + mi], k0 = BUFA[(mj+0)*32 + mi];
      float s1 = BUFB[(mj+1)*32 + mi], k1 = BUFA[(mj+1)*32 + mi];
      float s2 = BUFB[(mj+2)*32 + mi], k2 = BUFA[(mj+2)*32 + mi];
      float s3 = BUFB[(mj+3)*32 + mi], k3 = BUFA[(mj+3)*32 + mi];
      float4 o;
      o.x = 0.5f*(v.x + s0) + 0.5f*(k4.x + k0);
      o.y = 0.5f*(v.y + s1) + 0.5f*(k4.y + k1);
      o.z = 0.5f*(v.z + s2) + 0.5f*(k4.z + k2);
      o.w = 0.5f*(v.w + s3) + 0.5f*(k4.w + k3);
      st4(Sigma32 + mi*32 + mj, o);
    }
    __syncthreads();
  }

  // final filtered outputs for t = T-1
  st4((float*)(out + o_Sf + (btB + TT - 1)*1024 + tid*4), ld4(Sigma32 + tid*4));
  if (tid < 32) out[(btB + TT - 1)*32 + tid] = mu_lds[tid];
}

extern "C" void kernel_launch(void* const* d_in, const int* in_sizes, int n_in,
                              void* d_out, int out_size, void* d_ws, size_t ws_size,
                              hipStream_t stream) {
  const float* Y   = (const float*)d_in[0];
  const float* U   = (const float*)d_in[1];
  const float* Mk  = (const float*)d_in[2];
  const float* A   = (const float*)d_in[3];
  const float* Bm  = (const float*)d_in[4];
  const float* C   = (const float*)d_in[5];
  const float* mu0 = (const float*)d_in[6];
  const float* S0  = (const float*)d_in[7];
  const float* Q   = (const float*)d_in[8];
  const float* R   = (const float*)d_in[9];
  int Bsz = in_sizes[2] / TT;
  kf_kernel<<<Bsz, 256, 0, stream>>>(Y, U, Mk, A, Bm, C, mu0, S0, Q, R,
                                     (float*)d_out, Bsz);
}

// Round 2
// 2128.190 us; speedup vs baseline: 1.9379x; 1.9379x over previous
//
#include <hip/hip_runtime.h>
#include <math.h>

#define TT 200
#define PD 33   // padded stride for row-scalar-read left operands
#define ST 36   // padded stride (mult of 4) for T2/S/W buffers (33 cols used)

__device__ __forceinline__ float rdlane(float v, int l) {
  return __int_as_float(__builtin_amdgcn_readlane(__float_as_int(v), l));
}

#if __has_builtin(__builtin_amdgcn_rsqf)
#define RSQF(x) __builtin_amdgcn_rsqf(x)
#else
#define RSQF(x) (1.0f / sqrtf(x))
#endif

__device__ __forceinline__ float4 ld4(const float* p) { return *(const float4*)p; }
__device__ __forceinline__ void st4(float* p, float4 v) { *(float4*)p = v; }
__device__ __forceinline__ void fma4(float4& acc, float a, float4 b) {
  acc.x = fmaf(a, b.x, acc.x);
  acc.y = fmaf(a, b.y, acc.y);
  acc.z = fmaf(a, b.z, acc.z);
  acc.w = fmaf(a, b.w, acc.w);
}

__global__ void __launch_bounds__(256) kf_kernel(
    const float* __restrict__ Yg, const float* __restrict__ Ug,
    const float* __restrict__ Mg, const float* __restrict__ Ag,
    const float* __restrict__ Bg, const float* __restrict__ Cg,
    const float* __restrict__ mu0g, const float* __restrict__ S0g,
    const float* __restrict__ Qg, const float* __restrict__ Rg,
    float* __restrict__ out, int Bsz)
{
  __shared__ __align__(16) float Apad[32*PD], Cpad[32*PD], T1p[32*PD];
  __shared__ __align__(16) float AT32[1024], CT32[1024];
  __shared__ __align__(16) float Sigma32[1024], SigP32[1024];
  __shared__ __align__(16) float T2R[32*ST];   // T2 = C*SigP rows; col 32 = r
  __shared__ __align__(16) float SR[32*ST];    // S = T2*C^T + R
  __shared__ __align__(16) float WR[32*ST];    // W = L^-1 * [T2 | r], row-major
  __shared__ float u_lds[16], y_lds[32], mupred[32], mu_lds[32], mlds[1];

  const int tid = threadIdx.x;
  const int mi = tid >> 3;          // output row 0..31
  const int mj = (tid & 7) << 2;    // output col group (4 wide)
  const int b = blockIdx.x;
  const long btB = (long)b * TT;

  const long o_Sf = (long)Bsz * TT * 32;
  const long o_mp = o_Sf + (long)Bsz * TT * 32 * 32;
  const long o_Sp = o_mp + (long)Bsz * TT * 32;

  // constants + initial state
  for (int e = tid; e < 1024; e += 256) {
    int i = e >> 5, k = e & 31;
    float a = Ag[e];
    Apad[i*PD + k] = a; AT32[k*32 + i] = a;
    float c = Cg[e];
    Cpad[i*PD + k] = c; CT32[k*32 + i] = c;
    Sigma32[e] = S0g[e];
  }
  if (tid < 32) mu_lds[tid] = mu0g[tid];
  __syncthreads();

  for (int t = 0; t < TT; ++t) {
    const long bt = btB + t;

    // ---- P1: T1 = A @ Sigma ; stage u, y, mask ----
    {
      float4 acc = {0.f, 0.f, 0.f, 0.f};
      const int ro = mi * PD;
      #pragma unroll
      for (int k = 0; k < 32; ++k)
        fma4(acc, Apad[ro + k], ld4(Sigma32 + k*32 + mj));
      T1p[ro+mj] = acc.x; T1p[ro+mj+1] = acc.y; T1p[ro+mj+2] = acc.z; T1p[ro+mj+3] = acc.w;
      if (tid < 16) u_lds[tid] = Ug[bt*16 + tid];
      if (tid >= 64 && tid < 96) y_lds[tid-64] = Yg[bt*32 + (tid-64)];
      if (tid == 224) mlds[0] = Mg[bt];
    }
    __syncthreads();

    // ---- P2: SigP = T1 @ A^T + Q ; mu_pred = A mu + Bm u ----
    {
      float4 acc = {0.f, 0.f, 0.f, 0.f};
      const int ro = mi * PD;
      #pragma unroll
      for (int k = 0; k < 32; ++k)
        fma4(acc, T1p[ro + k], ld4(AT32 + k*32 + mj));
      float4 q4 = ld4(Qg + mi*32 + mj);
      acc.x += q4.x; acc.y += q4.y; acc.z += q4.z; acc.w += q4.w;
      st4(SigP32 + mi*32 + mj, acc);
      if (tid < 32) {
        float s = 0.f;
        #pragma unroll
        for (int k = 0; k < 32; ++k) s = fmaf(Apad[tid*PD + k], mu_lds[k], s);
        #pragma unroll
        for (int k = 0; k < 16; ++k) s = fmaf(Bg[tid*16 + k], u_lds[k], s);
        mupred[tid] = s;
      }
    }
    __syncthreads();

    // ---- P3: T2 = C @ SigP ; r = y - C mu_pred -> T2R col 32 ----
    {
      float4 acc = {0.f, 0.f, 0.f, 0.f};
      const int ro = mi * PD;
      #pragma unroll
      for (int k = 0; k < 32; ++k)
        fma4(acc, Cpad[ro + k], ld4(SigP32 + k*32 + mj));
      st4(T2R + mi*ST + mj, acc);
      if (tid < 32) {
        float s = y_lds[tid];
        #pragma unroll
        for (int k = 0; k < 32; ++k) s = fmaf(-Cpad[tid*PD + k], mupred[k], s);
        T2R[tid*ST + 32] = s;
      }
    }
    __syncthreads();

    // ---- P4: S = T2 @ C^T + R ----
    {
      float4 acc = {0.f, 0.f, 0.f, 0.f};
      const int ro = mi * ST;
      #pragma unroll
      for (int k = 0; k < 32; ++k)
        fma4(acc, T2R[ro + k], ld4(CT32 + k*32 + mj));
      float4 r4 = ld4(Rg + mi*32 + mj);
      acc.x += r4.x; acc.y += r4.y; acc.z += r4.z; acc.w += r4.w;
      st4(SR + mi*ST + mj, acc);
    }
    __syncthreads();

    // ---- P5: wave0: Cholesky of sym(S) fused with forward subst of [T2|r];
    //          waves1-3: stream outputs (SigP, mu_pred, prev Sigma_f/mu_f) ----
    if (tid < 64) {
      int c = tid; if (c > 32) c = 32;   // lanes 33-63 duplicate lane 32 (harmless)
      float w[32], rr[32];
      #pragma unroll
      for (int i = 0; i < 32; ++i) {
        w[i]  = 0.5f * (SR[i*ST + c] + SR[c*ST + i]);  // sym(S) column c
        rr[i] = T2R[i*ST + c];                          // RHS column c (c==32 -> r)
      }
      #pragma unroll
      for (int j = 0; j < 32; ++j) {
        float d  = rdlane(w[j], j);    // pivot (wave-uniform)
        float s  = RSQF(d);            // 1/L[j][j] (uniform)
        float cj = w[j] * s;           // L[c][j]
        float zj = rr[j] * s;          // z[j] for column c
        rr[j] = zj;
        WR[j*ST + c] = zj;             // W row j (conflict-free: banks 4j+c)
        float scj = s * cj;
        #pragma unroll
        for (int i = j+1; i < 32; ++i) {
          float bw = rdlane(w[i], j);            // Schur W[i][j] from lane j
          w[i]  = fmaf(-bw, scj, w[i]);          // Cholesky rank-1 update
          rr[i] = fmaf(-(bw * s), zj, rr[i]);    // fwd subst: L[i][j] = bw*s
        }
      }
    } else {
      const int g0 = tid - 64;
      for (int g = g0; g < 256; g += 192)
        st4((float*)(out + o_Sp + bt*1024 + g*4), ld4(SigP32 + g*4));
      if (t > 0) {
        for (int g = g0; g < 256; g += 192)
          st4((float*)(out + o_Sf + (bt-1)*1024 + g*4), ld4(Sigma32 + g*4));
      }
      if (tid >= 192 && tid < 224) out[o_mp + bt*32 + (tid-192)] = mupred[tid-192];
      if (t > 0 && tid >= 224) out[(bt-1)*32 + (tid-224)] = mu_lds[tid-224];
    }
    __syncthreads();

    // ---- P6: G = W^T W (exactly symmetric); Sigma' = SigP + (m^2-2m) G ;
    //          mu' = mu_pred + m * W^T w_r ----
    {
      const float m = mlds[0];
      const float coefS = fmaf(m, m, -2.f*m);   // m^2 - 2m
      float4 g = {0.f, 0.f, 0.f, 0.f};
      #pragma unroll
      for (int p = 0; p < 32; ++p)
        fma4(g, WR[p*ST + mi], ld4(WR + p*ST + mj));
      float4 sp = ld4(SigP32 + mi*32 + mj);
      float4 o;
      o.x = fmaf(coefS, g.x, sp.x);
      o.y = fmaf(coefS, g.y, sp.y);
      o.z = fmaf(coefS, g.z, sp.z);
      o.w = fmaf(coefS, g.w, sp.w);
      st4(Sigma32 + mi*32 + mj, o);
      if (tid < 32) {
        float sacc = 0.f;
        #pragma unroll
        for (int p = 0; p < 32; ++p)
          sacc = fmaf(WR[p*ST + tid], WR[p*ST + 32], sacc);
        mu_lds[tid] = fmaf(m, sacc, mupred[tid]);
      }
    }
    __syncthreads();
  }

  // final filtered outputs for t = T-1
  st4((float*)(out + o_Sf + (btB + TT - 1)*1024 + tid*4), ld4(Sigma32 + tid*4));
  if (tid < 32) out[(btB + TT - 1)*32 + tid] = mu_lds[tid];
}

extern "C" void kernel_launch(void* const* d_in, const int* in_sizes, int n_in,
                              void* d_out, int out_size, void* d_ws, size_t ws_size,
                              hipStream_t stream) {
  const float* Y   = (const float*)d_in[0];
  const float* U   = (const float*)d_in[1];
  const float* Mk  = (const float*)d_in[2];
  const float* A   = (const float*)d_in[3];
  const float* Bm  = (const float*)d_in[4];
  const float* C   = (const float*)d_in[5];
  const float* mu0 = (const float*)d_in[6];
  const float* S0  = (const float*)d_in[7];
  const float* Q   = (const float*)d_in[8];
  const float* R   = (const float*)d_in[9];
  int Bsz = in_sizes[2] / TT;
  kf_kernel<<<Bsz, 256, 0, stream>>>(Y, U, Mk, A, Bm, C, mu0, S0, Q, R,
                                     (float*)d_out, Bsz);
}